// Round 4
// baseline (189.765 us; speedup 1.0000x reference)
//
#include <hip/hip_runtime.h>

// QTT 3D sampling, round 4: digit-grouped GEMM, 8x4 micro-tile (M=32/block),
// wave-uniform A broadcast from LDS, async double-buffered B chunks, K-split 2
// for the 256x256 stages with partial-sum fused into the next stage's gather.
// Spill fixes: launch_bounds(256,4) (<=128 VGPR), no forced staging unrolls,
// unroll-1 k4 body with explicit components.
// Core shapes: (r_l, 8, r_{l+1}), ranks 1,8,64,256,256,256,64,8,1.
// C_l[k][d][s] at C_l[k*8*r_out + d*r_out + s].

typedef unsigned int u32;

__device__ __forceinline__ void async_load16(const float* g, float* l) {
    __builtin_amdgcn_global_load_lds(
        (const __attribute__((address_space(1))) u32*)g,
        (__attribute__((address_space(3))) u32*)l, 16, 0, 0);
}

__device__ __forceinline__ void fma4(float4& c, float a, const float4& b) {
    c.x = fmaf(a, b.x, c.x); c.y = fmaf(a, b.y, c.y);
    c.z = fmaf(a, b.z, c.z); c.w = fmaf(a, b.w, c.w);
}
__device__ __forceinline__ float4 f4add(float4 a, float4 b) {
    return make_float4(a.x + b.x, a.y + b.y, a.z + b.z, a.w + b.w);
}

// ---------------- prep: counting sort by digit, one block per level 2..5 -----
__global__ __launch_bounds__(256) void prep_kernel(const int* __restrict__ coords, int n,
                                                   int* __restrict__ perms,
                                                   int* __restrict__ bases)
{
    const int l = 2 + blockIdx.x;
    const int sh = 7 - l;
    __shared__ int cnt[8], offs[8];
    const int t = threadIdx.x;
    if (t < 8) cnt[t] = 0;
    __syncthreads();
    for (int i = t; i < n; i += 256) {
        const int d = 4*((coords[3*i]>>sh)&1) + 2*((coords[3*i+1]>>sh)&1)
                    + ((coords[3*i+2]>>sh)&1);
        atomicAdd(&cnt[d], 1);
    }
    __syncthreads();
    if (t == 0) {
        int run = 0;
        for (int d = 0; d < 8; ++d) {
            offs[d] = run;
            bases[(l-2)*9 + d] = run;
            run += cnt[d];
        }
        bases[(l-2)*9 + 8] = run;
    }
    __syncthreads();
    for (int i = t; i < n; i += 256) {
        const int d = 4*((coords[3*i]>>sh)&1) + 2*((coords[3*i+1]>>sh)&1)
                    + ((coords[3*i+2]>>sh)&1);
        const int pos = atomicAdd(&offs[d], 1);
        perms[(l-2)*n + pos] = i;
    }
}

// ---------------- init: v8 = C0[0,d0,:], v64 = v8 . C1[:,d1,:] ---------------
__global__ __launch_bounds__(256) void init_kernel(const float* __restrict__ C0,
                                                   const float* __restrict__ C1,
                                                   const int* __restrict__ coords,
                                                   float* __restrict__ V64, int n)
{
    const int idx = blockIdx.x * 256 + threadIdx.x;
    const int i = idx >> 6, c = idx & 63;
    if (i >= n) return;
    const int x = coords[3*i], y = coords[3*i+1], z = coords[3*i+2];
    const int d0 = 4*((x>>7)&1) + 2*((y>>7)&1) + ((z>>7)&1);
    const int d1 = 4*((x>>6)&1) + 2*((y>>6)&1) + ((z>>6)&1);
    const float* a = C0 + d0*8;
    const float* B = C1 + d1*64 + c;
    float acc = 0.f;
#pragma unroll
    for (int r = 0; r < 8; ++r) acc = fmaf(a[r], B[r*512], acc);
    V64[(size_t)i*64 + c] = acc;
}

// ---------------- N=256 grouped GEMM ----------------------------------------
// KTOT: Vin row stride. KSUB: K per block (blockIdx.z selects k-part).
// PARTS: input partial buffers to sum in the gather (1 or 2).
// Block: 32 samples x 256 cols. Wave wv owns samples [wv*8, wv*8+8); lane ln
// owns cols [ln*4, ln*4+4). A-read = wave-uniform b128 broadcast; B-read =
// lane-consecutive b128 (2-way bank alias, free).
template<int KTOT, int KSUB, int PARTS>
__global__ __launch_bounds__(256, 4) void gemm_n256(
    const float* __restrict__ Vin0, const float* __restrict__ Vin1,
    float* __restrict__ Vout, size_t outPartStride,
    const float* __restrict__ Ccore,
    const int* __restrict__ perm, const int* __restrict__ base)
{
    constexpr int KC  = 16;            // B chunk rows (double-buffered)
    constexpr int NCH = KSUB / KC;
    constexpr int AP  = KSUB + 4;

    const int d  = blockIdx.x;
    const int b0 = base[d], b1 = base[d + 1];
    const int nrows = b1 - b0;
    const int t = threadIdx.x, ln = t & 63, wv = t >> 6;
    const int kOff = (int)blockIdx.z * KSUB;

    __shared__ __align__(16) float Arm[32][AP];
    __shared__ __align__(16) float Bs[2][KC][256];

    const float* Cd = Ccore + d * 256;              // (k,c) at Cd[k*2048 + c]
    float* VoutP = Vout + (size_t)blockIdx.z * outPartStride;

    for (int tile = blockIdx.y; tile * 32 < nrows; tile += (int)gridDim.y) {
        const int row0 = b0 + tile * 32;

        // issue async B chunk 0 (1 KB row = 64 lanes x 16 B)
        for (int r = wv; r < KC; r += 4)
            async_load16(Cd + (size_t)(kOff + r) * 2048 + ln * 4, &Bs[0][r][ln * 4]);

        // gather A tile (32 x KSUB), coalesced f4, sum PARTS partials
        {
            constexpr int RF4 = KSUB / 4;
            for (int j = 0; j < (32 * RF4) / 256; ++j) {
                const int idx = t + 256 * j;
                const int s = idx / RF4, c4 = idx % RF4;
                const int gr = row0 + s;
                float4 v = make_float4(0.f, 0.f, 0.f, 0.f);
                if (gr < b1) {
                    const int rr = perm[gr];
                    const size_t o = (size_t)rr * KTOT + kOff + c4 * 4;
                    v = *(const float4*)(Vin0 + o);
                    if constexpr (PARTS == 2)
                        v = f4add(v, *(const float4*)(Vin1 + o));
                }
                *(float4*)&Arm[s][c4 * 4] = v;
            }
        }
        __syncthreads();                // Arm + chunk0 ready

        float4 acc[8];
#pragma unroll
        for (int i = 0; i < 8; ++i) acc[i] = make_float4(0.f, 0.f, 0.f, 0.f);

        for (int c = 0; c < NCH; ++c) {
            if (c + 1 < NCH) {
                const int nb = (c + 1) & 1;
                for (int r = wv; r < KC; r += 4)
                    async_load16(Cd + (size_t)(kOff + (c + 1) * KC + r) * 2048 + ln * 4,
                                 &Bs[nb][r][ln * 4]);
            }
            const int cb = c & 1;
            const int kb = c * KC;
#pragma unroll 1
            for (int k4 = 0; k4 < KC; k4 += 4) {
                float4 a[8];
#pragma unroll
                for (int i = 0; i < 8; ++i)
                    a[i] = *(const float4*)&Arm[wv * 8 + i][kb + k4];
                const float4 b0v = *(const float4*)&Bs[cb][k4 + 0][ln * 4];
                const float4 b1v = *(const float4*)&Bs[cb][k4 + 1][ln * 4];
                const float4 b2v = *(const float4*)&Bs[cb][k4 + 2][ln * 4];
                const float4 b3v = *(const float4*)&Bs[cb][k4 + 3][ln * 4];
#pragma unroll
                for (int i = 0; i < 8; ++i) {
                    fma4(acc[i], a[i].x, b0v);
                    fma4(acc[i], a[i].y, b1v);
                    fma4(acc[i], a[i].z, b2v);
                    fma4(acc[i], a[i].w, b3v);
                }
            }
            __syncthreads();            // chunk c+1 landed; buf c readers done
        }

        // write out: 8 rows x 4 cols per thread, 1 KB contiguous per row
#pragma unroll
        for (int i = 0; i < 8; ++i) {
            const int gr = row0 + wv * 8 + i;
            if (gr < b1) {
                const int rr = perm[gr];
                *(float4*)(VoutP + (size_t)rr * 256 + ln * 4) = acc[i];
            }
        }
        __syncthreads();                // protect Arm/Bs before next tile
    }
}

// ---------------- N=64 stage (C5): full slice in LDS, wave K-split 4 ---------
__global__ __launch_bounds__(256, 4) void gemm_n64(
    const float* __restrict__ Vin0, const float* __restrict__ Vin1,
    float* __restrict__ Vout, const float* __restrict__ C5,
    const int* __restrict__ perm, const int* __restrict__ base)
{
    const int d  = blockIdx.x;
    const int b0 = base[d], b1 = base[d + 1];
    const int nrows = b1 - b0;
    const int t = threadIdx.x, ln = t & 63, kp = t >> 6;
    const int cg = ln & 15, sg = ln >> 4;

    __shared__ __align__(16) float Bs[256][64];      // 64 KB, loaded once
    __shared__ __align__(16) float Arm[32][261];     // pad: 8*261 % 32 = 8
    __shared__ __align__(16) float4 red[4][32][16];  // 32 KB

    const float* Cd = C5 + d * 64;                   // (k,c) at Cd[k*512 + c]
    for (int j = 0; j < 16; ++j) {
        const int idx = t + 256 * j;                 // 4096 f4
        const int k = idx >> 4, c4 = idx & 15;
        *(float4*)&Bs[k][c4 * 4] = *(const float4*)(Cd + (size_t)k * 512 + c4 * 4);
    }

    for (int tile = blockIdx.y; tile * 32 < nrows; tile += (int)gridDim.y) {
        const int row0 = b0 + tile * 32;

        // gather A tile (32 x 256), summing the two K-partials of stage 4
        for (int j = 0; j < 8; ++j) {
            const int idx = t + 256 * j;
            const int s = idx >> 6, c4 = idx & 63;
            const int gr = row0 + s;
            float4 v = make_float4(0.f, 0.f, 0.f, 0.f);
            if (gr < b1) {
                const int rr = perm[gr];
                const size_t o = (size_t)rr * 256 + c4 * 4;
                v = f4add(*(const float4*)(Vin0 + o), *(const float4*)(Vin1 + o));
            }
            *(float4*)&Arm[s][c4 * 4] = v;
        }
        __syncthreads();                // Arm (and Bs on first tile) ready

        float4 acc[8];
#pragma unroll
        for (int i = 0; i < 8; ++i) acc[i] = make_float4(0.f, 0.f, 0.f, 0.f);

        const int k0 = kp * 64;
#pragma unroll 1
        for (int k4 = k0; k4 < k0 + 64; k4 += 4) {
            float4 a[8];
#pragma unroll
            for (int i = 0; i < 8; ++i)
                a[i] = *(const float4*)&Arm[sg * 8 + i][k4];
            const float4 b0v = *(const float4*)&Bs[k4 + 0][cg * 4];
            const float4 b1v = *(const float4*)&Bs[k4 + 1][cg * 4];
            const float4 b2v = *(const float4*)&Bs[k4 + 2][cg * 4];
            const float4 b3v = *(const float4*)&Bs[k4 + 3][cg * 4];
#pragma unroll
            for (int i = 0; i < 8; ++i) {
                fma4(acc[i], a[i].x, b0v);
                fma4(acc[i], a[i].y, b1v);
                fma4(acc[i], a[i].z, b2v);
                fma4(acc[i], a[i].w, b3v);
            }
        }
#pragma unroll
        for (int i = 0; i < 8; ++i) red[kp][sg * 8 + i][cg] = acc[i];
        __syncthreads();

        // reduce over kp and write: 512 f4 outputs, 2 per thread
        for (int j = 0; j < 2; ++j) {
            const int o = t * 2 + j;
            const int s = o >> 4, c4 = o & 15;
            float4 v = f4add(f4add(red[0][s][c4], red[1][s][c4]),
                             f4add(red[2][s][c4], red[3][s][c4]));
            const int gr = row0 + s;
            if (gr < b1) {
                const int rr = perm[gr];
                *(float4*)(Vout + (size_t)rr * 64 + c4 * 4) = v;
            }
        }
        __syncthreads();                // protect Arm/red before next tile
    }
}

// ---------------- final: v8 = v64 . C6[:,d6,:], out = v8 . C7[:,d7,0] --------
__global__ __launch_bounds__(256) void final_kernel(const float* __restrict__ V64,
                                                    const float* __restrict__ C6,
                                                    const float* __restrict__ C7,
                                                    const int* __restrict__ coords,
                                                    float* __restrict__ out, int n)
{
    const int t = threadIdx.x;
    const int i = blockIdx.x * 32 + (t >> 3);
    const int j = t & 7;
    if (i >= n) return;
    const int x = coords[3*i], y = coords[3*i+1], z = coords[3*i+2];
    const int d6 = 4*((x>>1)&1) + 2*((y>>1)&1) + ((z>>1)&1);
    const int d7 = 4*(x&1) + 2*(y&1) + (z&1);
    const float* v = V64 + (size_t)i*64;
    const float* B = C6 + d6*8 + j;
    float acc = 0.f;
#pragma unroll
    for (int r = 0; r < 64; ++r) acc = fmaf(v[r], B[r*64], acc);
    float m = acc * C7[j*8 + d7];
    m += __shfl_xor(m, 1);
    m += __shfl_xor(m, 2);
    m += __shfl_xor(m, 4);
    if (j == 0) out[i] = m;
}

extern "C" void kernel_launch(void* const* d_in, const int* in_sizes, int n_in,
                              void* d_out, int out_size, void* d_ws, size_t ws_size,
                              hipStream_t stream) {
    const float* C0 = (const float*)d_in[0];
    const float* C1 = (const float*)d_in[1];
    const float* C2 = (const float*)d_in[2];
    const float* C3 = (const float*)d_in[3];
    const float* C4 = (const float*)d_in[4];
    const float* C5 = (const float*)d_in[5];
    const float* C6 = (const float*)d_in[6];
    const float* C7 = (const float*)d_in[7];
    const int* coords = (const int*)d_in[8];
    float* out = (float*)d_out;

    const int n = in_sizes[8] / 3;

    // workspace (~23 MB for n=4096)
    float* V64  = (float*)d_ws;                       // n*64
    float* V2   = V64  + (size_t)n * 64;              // n*256
    float* V3p  = V2   + (size_t)n * 256;             // 2*n*256
    float* V4p  = V3p  + (size_t)n * 512;             // 2*n*256
    float* V5   = V4p  + (size_t)n * 512;             // n*64
    int*   perms = (int*)(V5 + (size_t)n * 64);       // 4*n
    int*   bases = perms + 4 * (size_t)n;             // 36

    const size_t ps = (size_t)n * 256;                // partial-buffer stride

    prep_kernel<<<4, 256, 0, stream>>>(coords, n, perms, bases);
    init_kernel<<<(n*64 + 255)/256, 256, 0, stream>>>(C0, C1, coords, V64, n);
    gemm_n256< 64,  64, 1><<<dim3(8, 16, 1), 256, 0, stream>>>(
        V64, V64, V2, 0, C2, perms + 0*n, bases + 0);
    gemm_n256<256, 128, 1><<<dim3(8, 16, 2), 256, 0, stream>>>(
        V2, V2, V3p, ps, C3, perms + 1*n, bases + 9);
    gemm_n256<256, 128, 2><<<dim3(8, 16, 2), 256, 0, stream>>>(
        V3p, V3p + ps, V4p, ps, C4, perms + 2*n, bases + 18);
    gemm_n64<<<dim3(8, 16), 256, 0, stream>>>(
        V4p, V4p + ps, V5, C5, perms + 3*n, bases + 27);
    final_kernel<<<(n + 31)/32, 256, 0, stream>>>(V5, C6, C7, coords, out, n);
}

// Round 5
// 185.852 us; speedup vs baseline: 1.0211x; 1.0211x over previous
//
#include <hip/hip_runtime.h>

// QTT 3D sampling, round 5.
// Pipeline: prep (ballot counting-sort, 4 levels) -> stage2 (fused init:
// C0*C1 -> v64 in-kernel, then x C2[d2]) -> stage3 -> stage4 (K-split 2,
// partial buffers) -> stage5 (N=64, K-split 2) -> final (sum partials,
// x C6[d6] x C7[d7], C6 in LDS).
// Occupancy fix vs r4: every GEMM stage launches 512 blocks (2/CU) with
// LDS <= 51 KB (3 resident); M-tile 16 (stage2: 8).
// Core shapes: (r_l, 8, r_{l+1}), ranks 1,8,64,256,256,256,64,8,1.
// C_l[k][d][s] at C_l[k*8*r_out + d*r_out + s].

typedef unsigned int u32;
typedef unsigned long long u64;

__device__ __forceinline__ void async_load16(const float* g, float* l) {
    __builtin_amdgcn_global_load_lds(
        (const __attribute__((address_space(1))) u32*)g,
        (__attribute__((address_space(3))) u32*)l, 16, 0, 0);
}
__device__ __forceinline__ void fma4(float4& c, float a, const float4& b) {
    c.x = fmaf(a, b.x, c.x); c.y = fmaf(a, b.y, c.y);
    c.z = fmaf(a, b.z, c.z); c.w = fmaf(a, b.w, c.w);
}
__device__ __forceinline__ float4 f4add(float4 a, float4 b) {
    return make_float4(a.x + b.x, a.y + b.y, a.z + b.z, a.w + b.w);
}
__device__ __forceinline__ int digit_of(int x, int y, int z, int sh) {
    return 4*((x>>sh)&1) + 2*((y>>sh)&1) + ((z>>sh)&1);
}

// ---------------- prep: ballot counting sort, block = level 2..5 -------------
__global__ __launch_bounds__(256) void prep_kernel(const int* __restrict__ coords, int n,
                                                   int* __restrict__ perms,
                                                   int* __restrict__ bases)
{
    const int l = 2 + blockIdx.x, sh = 7 - l;
    __shared__ int cnt[8], offs[8];
    const int t = threadIdx.x, ln = t & 63;
    if (t < 8) cnt[t] = 0;
    __syncthreads();

    for (int i0 = 0; i0 < n; i0 += 256) {
        const int i = i0 + t;
        const bool act = (i < n);
        int d = 0;
        if (act) d = digit_of(coords[3*i], coords[3*i+1], coords[3*i+2], sh);
#pragma unroll
        for (int dv = 0; dv < 8; ++dv) {
            const u64 m = __ballot(act && d == dv);
            if (ln == 0 && m) atomicAdd(&cnt[dv], __popcll(m));
        }
    }
    __syncthreads();
    if (t == 0) {
        int run = 0;
        for (int d = 0; d < 8; ++d) {
            offs[d] = run;
            bases[(l-2)*9 + d] = run;
            run += cnt[d];
        }
        bases[(l-2)*9 + 8] = run;
    }
    __syncthreads();

    for (int i0 = 0; i0 < n; i0 += 256) {
        const int i = i0 + t;
        const bool act = (i < n);
        int d = 0;
        if (act) d = digit_of(coords[3*i], coords[3*i+1], coords[3*i+2], sh);
#pragma unroll
        for (int dv = 0; dv < 8; ++dv) {
            const u64 m = __ballot(act && d == dv);
            if (!m) continue;
            const int leader = __ffsll((u64)m) - 1;
            int old = 0;
            if (ln == leader) old = atomicAdd(&offs[dv], __popcll(m));
            old = __shfl(old, leader);
            if (act && d == dv) {
                const int rank = __popcll(m & ((1ull << ln) - 1));
                perms[(l-2)*n + old + rank] = i;
            }
        }
    }
}

// ---------------- stage2: fused init (C0,C1) + GEMM vs C2[d2], M=8 -----------
__global__ __launch_bounds__(256, 4) void stage2_kernel(
    const float* __restrict__ C0, const float* __restrict__ C1,
    const float* __restrict__ C2, const int* __restrict__ coords,
    const int* __restrict__ perm, const int* __restrict__ base,
    float* __restrict__ Vout /* n x 256 */)
{
    constexpr int KC = 16;
    const int d = blockIdx.x;
    const int b0 = base[d], b1 = base[d+1];
    const int nrows = b1 - b0;
    const int t = threadIdx.x, ln = t & 63, wv = t >> 6;

    __shared__ float C0s[64];
    __shared__ __align__(16) float C1s[4096];
    __shared__ __align__(16) float Av[8][68];
    __shared__ __align__(16) float Bs[2][KC][256];
    __shared__ int rows[8], d0s[8], d1s[8];

    if (t < 64) C0s[t] = C0[t];
#pragma unroll
    for (int j = 0; j < 4; ++j)
        ((float4*)C1s)[t + 256*j] = ((const float4*)C1)[t + 256*j];

    const float* Cd = C2 + d * 256;            // (k,c) at Cd[k*2048 + c]

    for (int tile = blockIdx.y; tile * 8 < nrows; tile += (int)gridDim.y) {
        const int row0 = b0 + tile * 8;

        for (int r = wv; r < KC; r += 4)       // async B chunk 0
            async_load16(Cd + (size_t)r * 2048 + ln*4, &Bs[0][r][ln*4]);

        if (t < 8) {
            const int gr = row0 + t;
            const int rr = (gr < b1) ? perm[gr] : -1;
            rows[t] = rr;
            int d0 = 0, d1 = 0;
            if (rr >= 0) {
                const int x = coords[3*rr], y = coords[3*rr+1], z = coords[3*rr+2];
                d0 = digit_of(x, y, z, 7);
                d1 = digit_of(x, y, z, 6);
            }
            d0s[t] = d0; d1s[t] = d1;
        }
        __syncthreads();                       // rows/digits + C0s/C1s visible

        // v64 for 8 samples: 512 tasks, 2/thread
#pragma unroll
        for (int j = 0; j < 2; ++j) {
            const int idx = t + 256*j, s = idx >> 6, c = idx & 63;
            float acc = 0.f;
            if (rows[s] >= 0) {
                const int o0 = d0s[s]*8, o1 = d1s[s]*64;
#pragma unroll
                for (int r = 0; r < 8; ++r)
                    acc = fmaf(C0s[o0 + r], C1s[r*512 + o1 + c], acc);
            }
            Av[s][c] = acc;
        }
        __syncthreads();                       // Av + chunk0 ready

        float4 acc0 = make_float4(0,0,0,0), acc1 = make_float4(0,0,0,0);
        for (int c = 0; c < 4; ++c) {
            if (c + 1 < 4) {
                const int nb = (c+1) & 1;
                for (int r = wv; r < KC; r += 4)
                    async_load16(Cd + (size_t)((c+1)*KC + r)*2048 + ln*4,
                                 &Bs[nb][r][ln*4]);
            }
            const int cb = c & 1, kb = c * KC;
#pragma unroll 1
            for (int k4 = 0; k4 < KC; k4 += 4) {
                const float4 a0 = *(const float4*)&Av[wv*2 + 0][kb + k4];
                const float4 a1 = *(const float4*)&Av[wv*2 + 1][kb + k4];
                const float4 b0v = *(const float4*)&Bs[cb][k4+0][ln*4];
                const float4 b1v = *(const float4*)&Bs[cb][k4+1][ln*4];
                const float4 b2v = *(const float4*)&Bs[cb][k4+2][ln*4];
                const float4 b3v = *(const float4*)&Bs[cb][k4+3][ln*4];
                fma4(acc0, a0.x, b0v); fma4(acc0, a0.y, b1v);
                fma4(acc0, a0.z, b2v); fma4(acc0, a0.w, b3v);
                fma4(acc1, a1.x, b0v); fma4(acc1, a1.y, b1v);
                fma4(acc1, a1.z, b2v); fma4(acc1, a1.w, b3v);
            }
            __syncthreads();
        }
        {
            const int r0 = rows[wv*2 + 0], r1 = rows[wv*2 + 1];
            if (r0 >= 0) *(float4*)(Vout + (size_t)r0*256 + ln*4) = acc0;
            if (r1 >= 0) *(float4*)(Vout + (size_t)r1*256 + ln*4) = acc1;
        }
        __syncthreads();
    }
}

// ---------------- stages 3/4: 256->256, M=16, K-split 2 ----------------------
template<int PARTS>
__global__ __launch_bounds__(256, 4) void gemm_n256(
    const float* __restrict__ Vin0, const float* __restrict__ Vin1,
    float* __restrict__ Vout, size_t outPartStride,
    const float* __restrict__ Ccore,
    const int* __restrict__ perm, const int* __restrict__ base)
{
    constexpr int KSUB = 128, KC = 16, NCH = KSUB / KC;
    const int d = blockIdx.x;
    const int b0 = base[d], b1 = base[d+1];
    const int nrows = b1 - b0;
    const int t = threadIdx.x, ln = t & 63, wv = t >> 6;
    const int kOff = (int)blockIdx.z * KSUB;

    __shared__ __align__(16) float Arm[16][KSUB + 4];
    __shared__ __align__(16) float Bs[2][KC][256];
    __shared__ int rows[16];

    const float* Cd = Ccore + d * 256;
    float* VoutP = Vout + (size_t)blockIdx.z * outPartStride;

    for (int tile = blockIdx.y; tile * 16 < nrows; tile += (int)gridDim.y) {
        const int row0 = b0 + tile * 16;

        for (int r = wv; r < KC; r += 4)
            async_load16(Cd + (size_t)(kOff + r)*2048 + ln*4, &Bs[0][r][ln*4]);
        if (t < 16) rows[t] = (row0 + t < b1) ? perm[row0 + t] : -1;
        __syncthreads();                       // rows visible

        // gather A (16 x 128) = 512 f4, 2/thread; sum PARTS partials
#pragma unroll
        for (int j = 0; j < 2; ++j) {
            const int idx = t + 256*j, s = idx >> 5, c4 = idx & 31;
            const int rr = rows[s];
            float4 v = make_float4(0,0,0,0);
            if (rr >= 0) {
                const size_t o = (size_t)rr*256 + kOff + c4*4;
                v = *(const float4*)(Vin0 + o);
                if constexpr (PARTS == 2) v = f4add(v, *(const float4*)(Vin1 + o));
            }
            *(float4*)&Arm[s][c4*4] = v;
        }
        __syncthreads();                       // Arm + chunk0 ready

        float4 acc[4];
#pragma unroll
        for (int i = 0; i < 4; ++i) acc[i] = make_float4(0,0,0,0);

        for (int c = 0; c < NCH; ++c) {
            if (c + 1 < NCH) {
                const int nb = (c+1) & 1;
                for (int r = wv; r < KC; r += 4)
                    async_load16(Cd + (size_t)(kOff + (c+1)*KC + r)*2048 + ln*4,
                                 &Bs[nb][r][ln*4]);
            }
            const int cb = c & 1, kb = c * KC;
#pragma unroll 1
            for (int k4 = 0; k4 < KC; k4 += 4) {
                float4 a[4];
#pragma unroll
                for (int i = 0; i < 4; ++i)
                    a[i] = *(const float4*)&Arm[wv*4 + i][kb + k4];
                const float4 b0v = *(const float4*)&Bs[cb][k4+0][ln*4];
                const float4 b1v = *(const float4*)&Bs[cb][k4+1][ln*4];
                const float4 b2v = *(const float4*)&Bs[cb][k4+2][ln*4];
                const float4 b3v = *(const float4*)&Bs[cb][k4+3][ln*4];
#pragma unroll
                for (int i = 0; i < 4; ++i) {
                    fma4(acc[i], a[i].x, b0v);
                    fma4(acc[i], a[i].y, b1v);
                    fma4(acc[i], a[i].z, b2v);
                    fma4(acc[i], a[i].w, b3v);
                }
            }
            __syncthreads();
        }
#pragma unroll
        for (int i = 0; i < 4; ++i) {
            const int rr = rows[wv*4 + i];
            if (rr >= 0) *(float4*)(VoutP + (size_t)rr*256 + ln*4) = acc[i];
        }
        __syncthreads();
    }
}

// ---------------- stage5: 256->64, M=16, K-split 2, B resident ---------------
__global__ __launch_bounds__(256, 4) void gemm_n64(
    const float* __restrict__ Vin0, const float* __restrict__ Vin1,
    float* __restrict__ Vout, size_t outPartStride,
    const float* __restrict__ C5,
    const int* __restrict__ perm, const int* __restrict__ base)
{
    constexpr int KSUB = 128;
    const int d = blockIdx.x;
    const int b0 = base[d], b1 = base[d+1];
    const int nrows = b1 - b0;
    const int t = threadIdx.x;
    const int sg = t >> 4, cg = t & 15;
    const int kOff = (int)blockIdx.z * KSUB;

    __shared__ __align__(16) float Av[16][KSUB + 4];
    __shared__ __align__(16) float Bs[KSUB][64];
    __shared__ int rows[16];

    const float* Cd = C5 + d * 64;             // (k,c) at Cd[k*512 + c]
    float* VoutP = Vout + (size_t)blockIdx.z * outPartStride;

    // load B once (128 x 64 = 2048 f4, 8/thread)
#pragma unroll
    for (int j = 0; j < 8; ++j) {
        const int idx = t + 256*j, k = idx >> 4, c4 = idx & 15;
        *(float4*)&Bs[k][c4*4] =
            *(const float4*)(Cd + (size_t)(kOff + k)*512 + c4*4);
    }

    for (int tile = blockIdx.y; tile * 16 < nrows; tile += (int)gridDim.y) {
        const int row0 = b0 + tile * 16;
        if (t < 16) rows[t] = (row0 + t < b1) ? perm[row0 + t] : -1;
        __syncthreads();
#pragma unroll
        for (int j = 0; j < 2; ++j) {
            const int idx = t + 256*j, s = idx >> 5, c4 = idx & 31;
            const int rr = rows[s];
            float4 v = make_float4(0,0,0,0);
            if (rr >= 0) {
                const size_t o = (size_t)rr*256 + kOff + c4*4;
                v = f4add(*(const float4*)(Vin0 + o), *(const float4*)(Vin1 + o));
            }
            *(float4*)&Av[s][c4*4] = v;
        }
        __syncthreads();

        float4 acc = make_float4(0,0,0,0);
#pragma unroll 1
        for (int k4 = 0; k4 < KSUB; k4 += 4) {
            const float4 a = *(const float4*)&Av[sg][k4];
            const float4 b0v = *(const float4*)&Bs[k4+0][cg*4];
            const float4 b1v = *(const float4*)&Bs[k4+1][cg*4];
            const float4 b2v = *(const float4*)&Bs[k4+2][cg*4];
            const float4 b3v = *(const float4*)&Bs[k4+3][cg*4];
            fma4(acc, a.x, b0v); fma4(acc, a.y, b1v);
            fma4(acc, a.z, b2v); fma4(acc, a.w, b3v);
        }
        const int rr = rows[sg];
        if (rr >= 0) *(float4*)(VoutP + (size_t)rr*64 + cg*4) = acc;
        __syncthreads();
    }
}

// ---------------- final: sum K-partials, x C6[d6], x C7[d7] ------------------
__global__ __launch_bounds__(256) void final_kernel(
    const float* __restrict__ V5a, const float* __restrict__ V5b,
    const float* __restrict__ C6, const float* __restrict__ C7,
    const int* __restrict__ coords, float* __restrict__ out, int n)
{
    __shared__ __align__(16) float C6s[4096];
    __shared__ float C7s[64];
    const int t = threadIdx.x;
#pragma unroll
    for (int j = 0; j < 4; ++j)
        ((float4*)C6s)[t + 256*j] = ((const float4*)C6)[t + 256*j];
    if (t < 64) C7s[t] = C7[t];
    __syncthreads();

    const int i = blockIdx.x * 32 + (t >> 3);
    const int j = t & 7;
    if (i >= n) return;
    const int x = coords[3*i], y = coords[3*i+1], z = coords[3*i+2];
    const int d6 = digit_of(x, y, z, 1);
    const int d7 = digit_of(x, y, z, 0);
    const float* va = V5a + (size_t)i * 64;
    const float* vb = V5b + (size_t)i * 64;
    float acc = 0.f;
#pragma unroll 8
    for (int r = 0; r < 64; ++r)
        acc = fmaf(va[r] + vb[r], C6s[r*64 + d6*8 + j], acc);
    float m = acc * C7s[j*8 + d7];
    m += __shfl_xor(m, 1);
    m += __shfl_xor(m, 2);
    m += __shfl_xor(m, 4);
    if (j == 0) out[i] = m;
}

extern "C" void kernel_launch(void* const* d_in, const int* in_sizes, int n_in,
                              void* d_out, int out_size, void* d_ws, size_t ws_size,
                              hipStream_t stream) {
    const float* C0 = (const float*)d_in[0];
    const float* C1 = (const float*)d_in[1];
    const float* C2 = (const float*)d_in[2];
    const float* C3 = (const float*)d_in[3];
    const float* C4 = (const float*)d_in[4];
    const float* C5 = (const float*)d_in[5];
    const float* C6 = (const float*)d_in[6];
    const float* C7 = (const float*)d_in[7];
    const int* coords = (const int*)d_in[8];
    float* out = (float*)d_out;

    const int n = in_sizes[8] / 3;

    // workspace (~23 MB for n=4096)
    float* V2   = (float*)d_ws;                       // n*256
    float* V3p  = V2  + (size_t)n * 256;              // 2*n*256
    float* V4p  = V3p + (size_t)n * 512;              // 2*n*256
    float* V5p  = V4p + (size_t)n * 512;              // 2*n*64
    int*   perms = (int*)(V5p + (size_t)n * 128);     // 4*n
    int*   bases = perms + 4 * (size_t)n;             // 36

    const size_t ps   = (size_t)n * 256;              // 256-wide partial stride
    const size_t ps64 = (size_t)n * 64;               // 64-wide partial stride

    prep_kernel<<<4, 256, 0, stream>>>(coords, n, perms, bases);
    stage2_kernel<<<dim3(8, 64), 256, 0, stream>>>(
        C0, C1, C2, coords, perms + 0*n, bases + 0, V2);
    gemm_n256<1><<<dim3(8, 32, 2), 256, 0, stream>>>(
        V2, V2, V3p, ps, C3, perms + 1*n, bases + 9);
    gemm_n256<2><<<dim3(8, 32, 2), 256, 0, stream>>>(
        V3p, V3p + ps, V4p, ps, C4, perms + 2*n, bases + 18);
    gemm_n64<<<dim3(8, 32, 2), 256, 0, stream>>>(
        V4p, V4p + ps, V5p, ps64, C5, perms + 3*n, bases + 27);
    final_kernel<<<(n + 31)/32, 256, 0, stream>>>(
        V5p, V5p + ps64, C6, C7, coords, out, n);
}

// Round 6
// 152.871 us; speedup vs baseline: 1.2413x; 1.2157x over previous
//
#include <hip/hip_runtime.h>

// QTT 3D sampling, round 6: algebraic collapse + 2-GEMM core.
//   P2[d0,d1,d2] = C0[0,d0,:]·C1[:,d1,:]·C2[:,d2,:]   (512 x 256 table)
//   T [d5,d6,d7] = C5[:,d5,:]·C6[:,d6,:]·C7[:,d7,0]   (512 x 256 table)
//   V3 = gather(P2, prefix digits) x C3[d3]   (grouped GEMM, K-split 2)
//   V4 = V3 x C4[d4]                          (grouped GEMM, K-split 2)
//   out[i] = dot(V4[i], T[suffix digits(i)])
// Core shapes: (r_l, 8, r_{l+1}), ranks 1,8,64,256,256,256,64,8,1.
// C_l[k][d][s] at C_l[k*8*r_out + d*r_out + s].

typedef unsigned int u32;

__device__ __forceinline__ void async_load16(const float* g, float* l) {
    __builtin_amdgcn_global_load_lds(
        (const __attribute__((address_space(1))) u32*)g,
        (__attribute__((address_space(3))) u32*)l, 16, 0, 0);
}
__device__ __forceinline__ void fma4(float4& c, float a, const float4& b) {
    c.x = fmaf(a, b.x, c.x); c.y = fmaf(a, b.y, c.y);
    c.z = fmaf(a, b.z, c.z); c.w = fmaf(a, b.w, c.w);
}
__device__ __forceinline__ float4 f4add(float4 a, float4 b) {
    return make_float4(a.x + b.x, a.y + b.y, a.z + b.z, a.w + b.w);
}
__device__ __forceinline__ int digit_of(int x, int y, int z, int sh) {
    return 4*((x>>sh)&1) + 2*((y>>sh)&1) + ((z>>sh)&1);
}

// ---------------- prep: counting sort for levels 3 (sh 4) and 4 (sh 3) -------
// Per-thread LDS atomics + LDS digit cache; no serial ballot chains.
__global__ __launch_bounds__(256) void prep_kernel(const int* __restrict__ coords, int n,
                                                   int* __restrict__ perms,
                                                   int* __restrict__ bases)
{
    const int lvl = blockIdx.x;            // 0 -> level3, 1 -> level4
    const int sh  = 4 - lvl;
    __shared__ unsigned char digs[8192];
    __shared__ int cnt[8], offs[8];
    const int t = threadIdx.x;
    if (t < 8) cnt[t] = 0;
    __syncthreads();
    for (int i = t; i < n; i += 256) {
        const int d = digit_of(coords[3*i], coords[3*i+1], coords[3*i+2], sh);
        digs[i] = (unsigned char)d;
        atomicAdd(&cnt[d], 1);
    }
    __syncthreads();
    if (t == 0) {
        int run = 0;
        for (int d = 0; d < 8; ++d) {
            offs[d] = run;
            bases[lvl*9 + d] = run;
            run += cnt[d];
        }
        bases[lvl*9 + 8] = run;
    }
    __syncthreads();
    for (int i = t; i < n; i += 256) {
        const int pos = atomicAdd(&offs[digs[i]], 1);
        perms[lvl*n + pos] = i;
    }
}

// ---------------- tables: P2 (blocks 0..63) and T (blocks 64..127) -----------
__global__ __launch_bounds__(256, 4) void tables_kernel(
    const float* __restrict__ C0, const float* __restrict__ C1,
    const float* __restrict__ C2, const float* __restrict__ C5,
    const float* __restrict__ C6, const float* __restrict__ C7,
    float* __restrict__ P2, float* __restrict__ T)
{
    __shared__ union {
        struct { float P1s[8][64]; float4 red[4][8][64]; } a;   // P2 part
        struct { float S6s[8][64]; } b;                          // T part
    } u;
    const int t = threadIdx.x;

    if (blockIdx.x < 64) {
        // ---- P2 part: block = (d0, d2), all 8 d1 ----
        const int d0 = blockIdx.x & 7, d2 = blockIdx.x >> 3;
        // P1[d1][s] = sum_r C0[d0,r] * C1[r, d1, s]
#pragma unroll
        for (int j = 0; j < 2; ++j) {
            const int idx = t + 256*j, d1 = idx >> 6, s = idx & 63;
            float acc = 0.f;
#pragma unroll
            for (int r = 0; r < 8; ++r)
                acc = fmaf(C0[d0*8 + r], C1[r*512 + d1*64 + s], acc);
            u.a.P1s[d1][s] = acc;
        }
        __syncthreads();
        // P2[d0,d1,d2][col] = sum_k P1[d1][k] * C2[k, d2, col]
        const int col4 = t & 63, kp = t >> 6;
        float4 acc[8];
#pragma unroll
        for (int i = 0; i < 8; ++i) acc[i] = make_float4(0,0,0,0);
        for (int k = kp*16; k < kp*16 + 16; ++k) {
            const float4 c2 = *(const float4*)(C2 + (size_t)k*2048 + d2*256 + col4*4);
#pragma unroll
            for (int d1 = 0; d1 < 8; ++d1) fma4(acc[d1], u.a.P1s[d1][k], c2);
        }
#pragma unroll
        for (int d1 = 0; d1 < 8; ++d1) u.a.red[kp][d1][col4] = acc[d1];
        __syncthreads();
#pragma unroll
        for (int j = 0; j < 2; ++j) {
            const int idx = t + 256*j, d1 = idx >> 6, c4 = idx & 63;
            const float4 v = f4add(f4add(u.a.red[0][d1][c4], u.a.red[1][d1][c4]),
                                   f4add(u.a.red[2][d1][c4], u.a.red[3][d1][c4]));
            *(float4*)(P2 + (size_t)((d0*8 + d1)*8 + d2)*256 + c4*4) = v;
        }
    } else {
        // ---- T part: block = (d5, d6); all 8 d7 ----
        const int bb = blockIdx.x - 64;
        const int d5 = bb >> 3, d6 = bb & 7;
        // S6[d7][s] = sum_j C6[s, d6, j] * C7[j, d7]
#pragma unroll
        for (int j = 0; j < 2; ++j) {
            const int idx = t + 256*j, d7 = idx >> 6, s = idx & 63;
            float acc = 0.f;
#pragma unroll
            for (int jj = 0; jj < 8; ++jj)
                acc = fmaf(C6[s*64 + d6*8 + jj], C7[jj*8 + d7], acc);
            u.b.S6s[d7][s] = acc;
        }
        __syncthreads();
        // T[d5,d6,d7][k] = sum_s C5[k, d5, s] * S6[d7][s];  thread t owns k=t
        float4 creg[16];
#pragma unroll
        for (int s4 = 0; s4 < 16; ++s4)
            creg[s4] = *(const float4*)(C5 + (size_t)t*512 + d5*64 + s4*4);
#pragma unroll 1
        for (int d7 = 0; d7 < 8; ++d7) {
            float acc = 0.f;
#pragma unroll
            for (int s4 = 0; s4 < 16; ++s4) {
                const float4 a = creg[s4];
                const float4 b = *(const float4*)&u.b.S6s[d7][s4*4];
                acc = fmaf(a.x, b.x, acc); acc = fmaf(a.y, b.y, acc);
                acc = fmaf(a.z, b.z, acc); acc = fmaf(a.w, b.w, acc);
            }
            T[(size_t)((d5*8 + d6)*8 + d7)*256 + t] = acc;
        }
    }
}

// ---------------- stage3: A = P2[prefix digits], B = C3[d3], K-split 2 -------
__global__ __launch_bounds__(256, 4) void stage3_kernel(
    const float* __restrict__ P2, const float* __restrict__ C3,
    const int* __restrict__ coords,
    const int* __restrict__ perm, const int* __restrict__ base,
    float* __restrict__ V3, size_t ps)
{
    constexpr int KC = 16, NCH = 8;        // K = 128 per z-part
    const int d = blockIdx.x;
    const int b0 = base[d], b1 = base[d+1];
    const int nrows = b1 - b0;
    const int t = threadIdx.x, ln = t & 63, wv = t >> 6;
    const int kOff = (int)blockIdx.z * 128;

    __shared__ __align__(16) float Arm[16][132];
    __shared__ __align__(16) float Bs[2][KC][256];
    __shared__ int rows[16], pidx[16];

    const float* Cd = C3 + d * 256;
    float* VoutP = V3 + (size_t)blockIdx.z * ps;

    for (int tile = blockIdx.y; tile * 16 < nrows; tile += (int)gridDim.y) {
        const int row0 = b0 + tile * 16;

        for (int r = wv; r < KC; r += 4)
            async_load16(Cd + (size_t)(kOff + r)*2048 + ln*4, &Bs[0][r][ln*4]);
        if (t < 16) {
            const int gr = row0 + t;
            const int rr = (gr < b1) ? perm[gr] : -1;
            rows[t] = rr;
            int p = 0;
            if (rr >= 0) {
                const int x = coords[3*rr], y = coords[3*rr+1], z = coords[3*rr+2];
                p = digit_of(x,y,z,7)*64 + digit_of(x,y,z,6)*8 + digit_of(x,y,z,5);
            }
            pidx[t] = p;
        }
        __syncthreads();                    // rows/pidx visible

        // gather A (16 x 128) from P2 rows
#pragma unroll
        for (int j = 0; j < 2; ++j) {
            const int idx = t + 256*j, s = idx >> 5, c4 = idx & 31;
            float4 v = make_float4(0,0,0,0);
            if (rows[s] >= 0)
                v = *(const float4*)(P2 + (size_t)pidx[s]*256 + kOff + c4*4);
            *(float4*)&Arm[s][c4*4] = v;
        }
        __syncthreads();                    // Arm + chunk0 ready

        float4 acc[4];
#pragma unroll
        for (int i = 0; i < 4; ++i) acc[i] = make_float4(0,0,0,0);

        for (int c = 0; c < NCH; ++c) {
            if (c + 1 < NCH) {
                const int nb = (c+1) & 1;
                for (int r = wv; r < KC; r += 4)
                    async_load16(Cd + (size_t)(kOff + (c+1)*KC + r)*2048 + ln*4,
                                 &Bs[nb][r][ln*4]);
            }
            const int cb = c & 1, kb = c * KC;
#pragma unroll 1
            for (int k4 = 0; k4 < KC; k4 += 4) {
                float4 a[4];
#pragma unroll
                for (int i = 0; i < 4; ++i)
                    a[i] = *(const float4*)&Arm[wv*4 + i][kb + k4];
                const float4 b0v = *(const float4*)&Bs[cb][k4+0][ln*4];
                const float4 b1v = *(const float4*)&Bs[cb][k4+1][ln*4];
                const float4 b2v = *(const float4*)&Bs[cb][k4+2][ln*4];
                const float4 b3v = *(const float4*)&Bs[cb][k4+3][ln*4];
#pragma unroll
                for (int i = 0; i < 4; ++i) {
                    fma4(acc[i], a[i].x, b0v);
                    fma4(acc[i], a[i].y, b1v);
                    fma4(acc[i], a[i].z, b2v);
                    fma4(acc[i], a[i].w, b3v);
                }
            }
            __syncthreads();
        }
#pragma unroll
        for (int i = 0; i < 4; ++i) {
            const int rr = rows[wv*4 + i];
            if (rr >= 0) *(float4*)(VoutP + (size_t)rr*256 + ln*4) = acc[i];
        }
        __syncthreads();
    }
}

// ---------------- stage4: A = V3 (sum 2 partials), B = C4[d4], K-split 2 -----
__global__ __launch_bounds__(256, 4) void stage4_kernel(
    const float* __restrict__ Vin0, const float* __restrict__ Vin1,
    float* __restrict__ Vout, size_t ps,
    const float* __restrict__ C4,
    const int* __restrict__ perm, const int* __restrict__ base)
{
    constexpr int KC = 16, NCH = 8;
    const int d = blockIdx.x;
    const int b0 = base[d], b1 = base[d+1];
    const int nrows = b1 - b0;
    const int t = threadIdx.x, ln = t & 63, wv = t >> 6;
    const int kOff = (int)blockIdx.z * 128;

    __shared__ __align__(16) float Arm[16][132];
    __shared__ __align__(16) float Bs[2][KC][256];
    __shared__ int rows[16];

    const float* Cd = C4 + d * 256;
    float* VoutP = Vout + (size_t)blockIdx.z * ps;

    for (int tile = blockIdx.y; tile * 16 < nrows; tile += (int)gridDim.y) {
        const int row0 = b0 + tile * 16;

        for (int r = wv; r < KC; r += 4)
            async_load16(Cd + (size_t)(kOff + r)*2048 + ln*4, &Bs[0][r][ln*4]);
        if (t < 16) rows[t] = (row0 + t < b1) ? perm[row0 + t] : -1;
        __syncthreads();

#pragma unroll
        for (int j = 0; j < 2; ++j) {
            const int idx = t + 256*j, s = idx >> 5, c4 = idx & 31;
            const int rr = rows[s];
            float4 v = make_float4(0,0,0,0);
            if (rr >= 0) {
                const size_t o = (size_t)rr*256 + kOff + c4*4;
                v = f4add(*(const float4*)(Vin0 + o), *(const float4*)(Vin1 + o));
            }
            *(float4*)&Arm[s][c4*4] = v;
        }
        __syncthreads();

        float4 acc[4];
#pragma unroll
        for (int i = 0; i < 4; ++i) acc[i] = make_float4(0,0,0,0);

        for (int c = 0; c < NCH; ++c) {
            if (c + 1 < NCH) {
                const int nb = (c+1) & 1;
                for (int r = wv; r < KC; r += 4)
                    async_load16(Cd + (size_t)(kOff + (c+1)*KC + r)*2048 + ln*4,
                                 &Bs[nb][r][ln*4]);
            }
            const int cb = c & 1, kb = c * KC;
#pragma unroll 1
            for (int k4 = 0; k4 < KC; k4 += 4) {
                float4 a[4];
#pragma unroll
                for (int i = 0; i < 4; ++i)
                    a[i] = *(const float4*)&Arm[wv*4 + i][kb + k4];
                const float4 b0v = *(const float4*)&Bs[cb][k4+0][ln*4];
                const float4 b1v = *(const float4*)&Bs[cb][k4+1][ln*4];
                const float4 b2v = *(const float4*)&Bs[cb][k4+2][ln*4];
                const float4 b3v = *(const float4*)&Bs[cb][k4+3][ln*4];
#pragma unroll
                for (int i = 0; i < 4; ++i) {
                    fma4(acc[i], a[i].x, b0v);
                    fma4(acc[i], a[i].y, b1v);
                    fma4(acc[i], a[i].z, b2v);
                    fma4(acc[i], a[i].w, b3v);
                }
            }
            __syncthreads();
        }
#pragma unroll
        for (int i = 0; i < 4; ++i) {
            const int rr = rows[wv*4 + i];
            if (rr >= 0) *(float4*)(VoutP + (size_t)rr*256 + ln*4) = acc[i];
        }
        __syncthreads();
    }
}

// ---------------- final: out[i] = dot(V4a[i] + V4b[i], T[suffix(i)]) ---------
__global__ __launch_bounds__(256) void final_kernel(
    const float* __restrict__ V4a, const float* __restrict__ V4b,
    const float* __restrict__ T, const int* __restrict__ coords,
    float* __restrict__ out, int n)
{
    __shared__ int qs[8];
    const int t = threadIdx.x;
    const int base = blockIdx.x * 8;
    if (t < 8) {
        const int i = base + t;
        int q = 0;
        if (i < n) {
            const int x = coords[3*i], y = coords[3*i+1], z = coords[3*i+2];
            q = digit_of(x,y,z,2)*64 + digit_of(x,y,z,1)*8 + digit_of(x,y,z,0);
        }
        qs[t] = q;
    }
    __syncthreads();
    const int s = t >> 5, lane = t & 31;
    const int i = base + s;
    if (i >= n) return;
    const float* va = V4a + (size_t)i*256 + lane*8;
    const float* vb = V4b + (size_t)i*256 + lane*8;
    const float* tr = T + (size_t)qs[s]*256 + lane*8;
    float acc = 0.f;
#pragma unroll
    for (int j = 0; j < 2; ++j) {
        const float4 a = f4add(*(const float4*)(va + j*4), *(const float4*)(vb + j*4));
        const float4 b = *(const float4*)(tr + j*4);
        acc = fmaf(a.x, b.x, acc); acc = fmaf(a.y, b.y, acc);
        acc = fmaf(a.z, b.z, acc); acc = fmaf(a.w, b.w, acc);
    }
    acc += __shfl_xor(acc, 1);
    acc += __shfl_xor(acc, 2);
    acc += __shfl_xor(acc, 4);
    acc += __shfl_xor(acc, 8);
    acc += __shfl_xor(acc, 16);
    if (lane == 0) out[i] = acc;
}

extern "C" void kernel_launch(void* const* d_in, const int* in_sizes, int n_in,
                              void* d_out, int out_size, void* d_ws, size_t ws_size,
                              hipStream_t stream) {
    const float* C0 = (const float*)d_in[0];
    const float* C1 = (const float*)d_in[1];
    const float* C2 = (const float*)d_in[2];
    const float* C3 = (const float*)d_in[3];
    const float* C4 = (const float*)d_in[4];
    const float* C5 = (const float*)d_in[5];
    const float* C6 = (const float*)d_in[6];
    const float* C7 = (const float*)d_in[7];
    const int* coords = (const int*)d_in[8];
    float* out = (float*)d_out;

    const int n = in_sizes[8] / 3;

    // workspace (~18 MB for n=4096)
    float* P2   = (float*)d_ws;                       // 512*256
    float* Tt   = P2  + 512*256;                      // 512*256
    float* V3p  = Tt  + 512*256;                      // 2*n*256
    float* V4p  = V3p + (size_t)n * 512;              // 2*n*256
    int*   perms = (int*)(V4p + (size_t)n * 512);     // 2*n
    int*   bases = perms + 2 * (size_t)n;             // 18

    const size_t ps = (size_t)n * 256;

    prep_kernel<<<2, 256, 0, stream>>>(coords, n, perms, bases);
    tables_kernel<<<128, 256, 0, stream>>>(C0, C1, C2, C5, C6, C7, P2, Tt);
    stage3_kernel<<<dim3(8, 32, 2), 256, 0, stream>>>(
        P2, C3, coords, perms + 0*n, bases + 0, V3p, ps);
    stage4_kernel<<<dim3(8, 32, 2), 256, 0, stream>>>(
        V3p, V3p + ps, V4p, ps, C4, perms + 1*n, bases + 9);
    final_kernel<<<(n + 7)/8, 256, 0, stream>>>(
        V4p, V4p + ps, Tt, coords, out, n);
}

// Round 7
// 138.978 us; speedup vs baseline: 1.3654x; 1.1000x over previous
//
#include <hip/hip_runtime.h>

// QTT 3D sampling, round 7: 3-dispatch pipeline.
//   K1: prep (counting sort, levels d3/d4) + tables P2 = C0·C1·C2, T = C5·C6·C7
//   K2: V3 = gather(P2, prefix) x C3[d3]   (grouped GEMM, K-split 2)
//   K3: V4 = (V3a+V3b) x C4[d4], fused epilogue out[i] = dot(V4[i], T[suffix])
// Core shapes: (r_l, 8, r_{l+1}), ranks 1,8,64,256,256,256,64,8,1.
// C_l[k][d][s] at C_l[k*8*r_out + d*r_out + s].

typedef unsigned int u32;

__device__ __forceinline__ void async_load16(const float* g, float* l) {
    __builtin_amdgcn_global_load_lds(
        (const __attribute__((address_space(1))) u32*)g,
        (__attribute__((address_space(3))) u32*)l, 16, 0, 0);
}
__device__ __forceinline__ void fma4(float4& c, float a, const float4& b) {
    c.x = fmaf(a, b.x, c.x); c.y = fmaf(a, b.y, c.y);
    c.z = fmaf(a, b.z, c.z); c.w = fmaf(a, b.w, c.w);
}
__device__ __forceinline__ float4 f4add(float4 a, float4 b) {
    return make_float4(a.x + b.x, a.y + b.y, a.z + b.z, a.w + b.w);
}
__device__ __forceinline__ int digit_of(int x, int y, int z, int sh) {
    return 4*((x>>sh)&1) + 2*((y>>sh)&1) + ((z>>sh)&1);
}

// ---------------- K1: prep (blocks 0,1) + P2 table (2..65) + T table (66..129)
__global__ __launch_bounds__(256) void prep_tables_kernel(
    const float* __restrict__ C0, const float* __restrict__ C1,
    const float* __restrict__ C2, const float* __restrict__ C5,
    const float* __restrict__ C6, const float* __restrict__ C7,
    const int* __restrict__ coords, int n,
    int* __restrict__ perms, int* __restrict__ bases,
    float* __restrict__ P2, float* __restrict__ T)
{
    __shared__ union {
        struct { unsigned char digs[8192]; int cnt[8]; int offs[8]; } p;
        struct { float P1s[8][64]; float4 red[4][8][64]; } a;
        struct { float S6s[8][64]; } b;
    } u;
    const int t = threadIdx.x;
    const int bx = blockIdx.x;

    if (bx < 2) {
        // ---- prep: counting sort by digit; lvl 0 -> d3 (sh 4), lvl 1 -> d4 (sh 3)
        const int lvl = bx, sh = 4 - lvl;
        if (t < 8) u.p.cnt[t] = 0;
        __syncthreads();
        for (int i = t; i < n; i += 256) {
            const int d = digit_of(coords[3*i], coords[3*i+1], coords[3*i+2], sh);
            u.p.digs[i] = (unsigned char)d;
            atomicAdd(&u.p.cnt[d], 1);
        }
        __syncthreads();
        if (t == 0) {
            int run = 0;
            for (int d = 0; d < 8; ++d) {
                u.p.offs[d] = run;
                bases[lvl*9 + d] = run;
                run += u.p.cnt[d];
            }
            bases[lvl*9 + 8] = run;
        }
        __syncthreads();
        for (int i = t; i < n; i += 256) {
            const int pos = atomicAdd(&u.p.offs[u.p.digs[i]], 1);
            perms[lvl*n + pos] = i;
        }
    } else if (bx < 66) {
        // ---- P2 part: block = (d0, d2), all 8 d1 ----
        const int bb = bx - 2;
        const int d0 = bb & 7, d2 = bb >> 3;
#pragma unroll
        for (int j = 0; j < 2; ++j) {
            const int idx = t + 256*j, d1 = idx >> 6, s = idx & 63;
            float acc = 0.f;
#pragma unroll
            for (int r = 0; r < 8; ++r)
                acc = fmaf(C0[d0*8 + r], C1[r*512 + d1*64 + s], acc);
            u.a.P1s[d1][s] = acc;
        }
        __syncthreads();
        const int col4 = t & 63, kp = t >> 6;
        float4 acc[8];
#pragma unroll
        for (int i = 0; i < 8; ++i) acc[i] = make_float4(0,0,0,0);
        for (int k = kp*16; k < kp*16 + 16; ++k) {
            const float4 c2 = *(const float4*)(C2 + (size_t)k*2048 + d2*256 + col4*4);
#pragma unroll
            for (int d1 = 0; d1 < 8; ++d1) fma4(acc[d1], u.a.P1s[d1][k], c2);
        }
#pragma unroll
        for (int d1 = 0; d1 < 8; ++d1) u.a.red[kp][d1][col4] = acc[d1];
        __syncthreads();
#pragma unroll
        for (int j = 0; j < 2; ++j) {
            const int idx = t + 256*j, d1 = idx >> 6, c4 = idx & 63;
            const float4 v = f4add(f4add(u.a.red[0][d1][c4], u.a.red[1][d1][c4]),
                                   f4add(u.a.red[2][d1][c4], u.a.red[3][d1][c4]));
            *(float4*)(P2 + (size_t)((d0*8 + d1)*8 + d2)*256 + c4*4) = v;
        }
    } else {
        // ---- T part: block = (d5, d6); all 8 d7 ----
        const int bb = bx - 66;
        const int d5 = bb >> 3, d6 = bb & 7;
#pragma unroll
        for (int j = 0; j < 2; ++j) {
            const int idx = t + 256*j, d7 = idx >> 6, s = idx & 63;
            float acc = 0.f;
#pragma unroll
            for (int jj = 0; jj < 8; ++jj)
                acc = fmaf(C6[s*64 + d6*8 + jj], C7[jj*8 + d7], acc);
            u.b.S6s[d7][s] = acc;
        }
        __syncthreads();
        float4 creg[16];
#pragma unroll
        for (int s4 = 0; s4 < 16; ++s4)
            creg[s4] = *(const float4*)(C5 + (size_t)t*512 + d5*64 + s4*4);
#pragma unroll 1
        for (int d7 = 0; d7 < 8; ++d7) {
            float acc = 0.f;
#pragma unroll
            for (int s4 = 0; s4 < 16; ++s4) {
                const float4 a = creg[s4];
                const float4 b = *(const float4*)&u.b.S6s[d7][s4*4];
                acc = fmaf(a.x, b.x, acc); acc = fmaf(a.y, b.y, acc);
                acc = fmaf(a.z, b.z, acc); acc = fmaf(a.w, b.w, acc);
            }
            T[(size_t)((d5*8 + d6)*8 + d7)*256 + t] = acc;
        }
    }
}

// ---------------- K2: stage3: A = P2[prefix digits], B = C3[d3], K-split 2 ---
__global__ __launch_bounds__(256, 4) void stage3_kernel(
    const float* __restrict__ P2, const float* __restrict__ C3,
    const int* __restrict__ coords,
    const int* __restrict__ perm, const int* __restrict__ base,
    float* __restrict__ V3, size_t ps)
{
    constexpr int KC = 16, NCH = 8;        // K = 128 per z-part
    const int d = blockIdx.x;
    const int b0 = base[d], b1 = base[d+1];
    const int nrows = b1 - b0;
    const int t = threadIdx.x, ln = t & 63, wv = t >> 6;
    const int kOff = (int)blockIdx.z * 128;

    __shared__ __align__(16) float Arm[16][132];
    __shared__ __align__(16) float Bs[2][KC][256];
    __shared__ int rows[16], pidx[16];

    const float* Cd = C3 + d * 256;
    float* VoutP = V3 + (size_t)blockIdx.z * ps;

    for (int tile = blockIdx.y; tile * 16 < nrows; tile += (int)gridDim.y) {
        const int row0 = b0 + tile * 16;

        for (int r = wv; r < KC; r += 4)
            async_load16(Cd + (size_t)(kOff + r)*2048 + ln*4, &Bs[0][r][ln*4]);
        if (t < 16) {
            const int gr = row0 + t;
            const int rr = (gr < b1) ? perm[gr] : -1;
            rows[t] = rr;
            int p = 0;
            if (rr >= 0) {
                const int x = coords[3*rr], y = coords[3*rr+1], z = coords[3*rr+2];
                p = digit_of(x,y,z,7)*64 + digit_of(x,y,z,6)*8 + digit_of(x,y,z,5);
            }
            pidx[t] = p;
        }
        __syncthreads();

#pragma unroll
        for (int j = 0; j < 2; ++j) {
            const int idx = t + 256*j, s = idx >> 5, c4 = idx & 31;
            float4 v = make_float4(0,0,0,0);
            if (rows[s] >= 0)
                v = *(const float4*)(P2 + (size_t)pidx[s]*256 + kOff + c4*4);
            *(float4*)&Arm[s][c4*4] = v;
        }
        __syncthreads();

        float4 acc[4];
#pragma unroll
        for (int i = 0; i < 4; ++i) acc[i] = make_float4(0,0,0,0);

        for (int c = 0; c < NCH; ++c) {
            if (c + 1 < NCH) {
                const int nb = (c+1) & 1;
                for (int r = wv; r < KC; r += 4)
                    async_load16(Cd + (size_t)(kOff + (c+1)*KC + r)*2048 + ln*4,
                                 &Bs[nb][r][ln*4]);
            }
            const int cb = c & 1, kb = c * KC;
#pragma unroll 1
            for (int k4 = 0; k4 < KC; k4 += 4) {
                float4 a[4];
#pragma unroll
                for (int i = 0; i < 4; ++i)
                    a[i] = *(const float4*)&Arm[wv*4 + i][kb + k4];
                const float4 b0v = *(const float4*)&Bs[cb][k4+0][ln*4];
                const float4 b1v = *(const float4*)&Bs[cb][k4+1][ln*4];
                const float4 b2v = *(const float4*)&Bs[cb][k4+2][ln*4];
                const float4 b3v = *(const float4*)&Bs[cb][k4+3][ln*4];
#pragma unroll
                for (int i = 0; i < 4; ++i) {
                    fma4(acc[i], a[i].x, b0v);
                    fma4(acc[i], a[i].y, b1v);
                    fma4(acc[i], a[i].z, b2v);
                    fma4(acc[i], a[i].w, b3v);
                }
            }
            __syncthreads();
        }
#pragma unroll
        for (int i = 0; i < 4; ++i) {
            const int rr = rows[wv*4 + i];
            if (rr >= 0) *(float4*)(VoutP + (size_t)rr*256 + ln*4) = acc[i];
        }
        __syncthreads();
    }
}

// ---------------- K3: stage4 (full K=256, M=8) + fused final epilogue --------
__global__ __launch_bounds__(256, 4) void stage4_final_kernel(
    const float* __restrict__ Vin0, const float* __restrict__ Vin1,
    const float* __restrict__ C4, const float* __restrict__ T,
    const int* __restrict__ coords,
    const int* __restrict__ perm, const int* __restrict__ base,
    float* __restrict__ out)
{
    constexpr int KC = 16, NCH = 16;       // K = 256
    const int d = blockIdx.x;
    const int b0 = base[d], b1 = base[d+1];
    const int nrows = b1 - b0;
    const int t = threadIdx.x, ln = t & 63, wv = t >> 6;

    __shared__ __align__(16) float Arm[8][260];
    __shared__ __align__(16) float Bs[2][KC][256];
    __shared__ int rows[8], qs[8];

    const float* Cd = C4 + d * 256;

    for (int tile = blockIdx.y; tile * 8 < nrows; tile += (int)gridDim.y) {
        const int row0 = b0 + tile * 8;

        for (int r = wv; r < KC; r += 4)
            async_load16(Cd + (size_t)r*2048 + ln*4, &Bs[0][r][ln*4]);
        if (t < 8) {
            const int gr = row0 + t;
            const int rr = (gr < b1) ? perm[gr] : -1;
            rows[t] = rr;
            int q = 0;
            if (rr >= 0) {
                const int x = coords[3*rr], y = coords[3*rr+1], z = coords[3*rr+2];
                q = digit_of(x,y,z,2)*64 + digit_of(x,y,z,1)*8 + digit_of(x,y,z,0);
            }
            qs[t] = q;
        }
        __syncthreads();

        // gather A (8 x 256) = 512 f4, 2/thread; sum the 2 stage-3 K-partials
#pragma unroll
        for (int j = 0; j < 2; ++j) {
            const int idx = t + 256*j, s = idx >> 6, c4 = idx & 63;
            const int rr = rows[s];
            float4 v = make_float4(0,0,0,0);
            if (rr >= 0) {
                const size_t o = (size_t)rr*256 + c4*4;
                v = f4add(*(const float4*)(Vin0 + o), *(const float4*)(Vin1 + o));
            }
            *(float4*)&Arm[s][c4*4] = v;
        }
        __syncthreads();

        float4 acc0 = make_float4(0,0,0,0), acc1 = make_float4(0,0,0,0);

        for (int c = 0; c < NCH; ++c) {
            if (c + 1 < NCH) {
                const int nb = (c+1) & 1;
                for (int r = wv; r < KC; r += 4)
                    async_load16(Cd + (size_t)((c+1)*KC + r)*2048 + ln*4,
                                 &Bs[nb][r][ln*4]);
            }
            const int cb = c & 1, kb = c * KC;
#pragma unroll 1
            for (int k4 = 0; k4 < KC; k4 += 4) {
                const float4 a0 = *(const float4*)&Arm[wv*2 + 0][kb + k4];
                const float4 a1 = *(const float4*)&Arm[wv*2 + 1][kb + k4];
                const float4 b0v = *(const float4*)&Bs[cb][k4+0][ln*4];
                const float4 b1v = *(const float4*)&Bs[cb][k4+1][ln*4];
                const float4 b2v = *(const float4*)&Bs[cb][k4+2][ln*4];
                const float4 b3v = *(const float4*)&Bs[cb][k4+3][ln*4];
                fma4(acc0, a0.x, b0v); fma4(acc0, a0.y, b1v);
                fma4(acc0, a0.z, b2v); fma4(acc0, a0.w, b3v);
                fma4(acc1, a1.x, b0v); fma4(acc1, a1.y, b1v);
                fma4(acc1, a1.z, b2v); fma4(acc1, a1.w, b3v);
            }
            __syncthreads();
        }

        // fused final: out[rr] = dot(V4row, T[q]); wave wv owns rows wv*2+{0,1}
#pragma unroll
        for (int i = 0; i < 2; ++i) {
            const int s = wv*2 + i;
            const int rr = rows[s];
            float p = 0.f;
            if (rr >= 0) {
                const float4 a = (i == 0) ? acc0 : acc1;
                const float4 tv = *(const float4*)(T + (size_t)qs[s]*256 + ln*4);
                p = fmaf(a.x, tv.x, fmaf(a.y, tv.y, fmaf(a.z, tv.z, a.w * tv.w)));
            }
            p += __shfl_xor(p, 1);
            p += __shfl_xor(p, 2);
            p += __shfl_xor(p, 4);
            p += __shfl_xor(p, 8);
            p += __shfl_xor(p, 16);
            p += __shfl_xor(p, 32);
            if (ln == 0 && rr >= 0) out[rr] = p;
        }
        __syncthreads();
    }
}

extern "C" void kernel_launch(void* const* d_in, const int* in_sizes, int n_in,
                              void* d_out, int out_size, void* d_ws, size_t ws_size,
                              hipStream_t stream) {
    const float* C0 = (const float*)d_in[0];
    const float* C1 = (const float*)d_in[1];
    const float* C2 = (const float*)d_in[2];
    const float* C3 = (const float*)d_in[3];
    const float* C4 = (const float*)d_in[4];
    const float* C5 = (const float*)d_in[5];
    const float* C6 = (const float*)d_in[6];
    const float* C7 = (const float*)d_in[7];
    const int* coords = (const int*)d_in[8];
    float* out = (float*)d_out;

    const int n = in_sizes[8] / 3;

    // workspace (~9.5 MB for n=4096)
    float* P2   = (float*)d_ws;                       // 512*256
    float* Tt   = P2  + 512*256;                      // 512*256
    float* V3p  = Tt  + 512*256;                      // 2*n*256
    int*   perms = (int*)(V3p + (size_t)n * 512);     // 2*n
    int*   bases = perms + 2 * (size_t)n;             // 18

    const size_t ps = (size_t)n * 256;

    prep_tables_kernel<<<130, 256, 0, stream>>>(
        C0, C1, C2, C5, C6, C7, coords, n, perms, bases, P2, Tt);
    stage3_kernel<<<dim3(8, 32, 2), 256, 0, stream>>>(
        P2, C3, coords, perms + 0*n, bases + 0, V3p, ps);
    stage4_final_kernel<<<dim3(8, 64), 256, 0, stream>>>(
        V3p, V3p + ps, C4, Tt, coords, perms + 1*n, bases + 9, out);
}

// Round 9
// 125.448 us; speedup vs baseline: 1.5127x; 1.1079x over previous
//
#include <hip/hip_runtime.h>

// QTT 3D sampling, round 9: 2-dispatch pipeline, no inter-stage sort-gather.
//   K1 (577 blocks, independent parts):
//     block 0      : counting sort of samples by d4 (perms/bases)
//     blocks 1-64  : T[d5,d6,d7] = C5·(C6·C7)          (512 x 256 table)
//     blocks 65-576: P3[d0,d1,d2,d3] = C0·C1·C2·C3     (4096 x 256 table)
//                    block = (d0,d2,d3); 8 rows (d1) built in-LDS from
//                    C0/C1/C2, then K=256 GEMM vs C3[d3] (async dbuf chunks)
//   K2 (512 blocks): V4 = gather(P3, prefix4) x C4[d4] (d4-grouped GEMM),
//                    fused epilogue out[i] = dot(V4row, T[suffix3])
// Core shapes: (r_l, 8, r_{l+1}), ranks 1,8,64,256,256,256,64,8,1.
// C_l[k][d][s] at C_l[k*8*r_out + d*r_out + s].

typedef unsigned int u32;

__device__ __forceinline__ void async_load16(const float* g, float* l) {
    __builtin_amdgcn_global_load_lds(
        (const __attribute__((address_space(1))) u32*)g,
        (__attribute__((address_space(3))) u32*)l, 16, 0, 0);
}
__device__ __forceinline__ void fma4(float4& c, float a, const float4& b) {
    c.x = fmaf(a, b.x, c.x); c.y = fmaf(a, b.y, c.y);
    c.z = fmaf(a, b.z, c.z); c.w = fmaf(a, b.w, c.w);
}
__device__ __forceinline__ int digit_of(int x, int y, int z, int sh) {
    return 4*((x>>sh)&1) + 2*((y>>sh)&1) + ((z>>sh)&1);
}

// ---------------- K1: prep + T table + dense P3 table ------------------------
__global__ __launch_bounds__(256, 4) void tables_kernel(
    const float* __restrict__ C0, const float* __restrict__ C1,
    const float* __restrict__ C2, const float* __restrict__ C3,
    const float* __restrict__ C5, const float* __restrict__ C6,
    const float* __restrict__ C7,
    const int* __restrict__ coords, int n,
    int* __restrict__ perms, int* __restrict__ bases,
    float* __restrict__ P3, float* __restrict__ T)
{
    __shared__ __align__(16) union {
        struct { unsigned char digs[8192]; int cnt[8]; int offs[8]; } p;
        struct { float S6s[8][64]; } b;
        struct { float v64[8][64]; float As[8][260]; float Bs[2][16][256]; } g;
    } u;
    const int t = threadIdx.x;
    const int ln = t & 63, wv = t >> 6;
    const int bx = blockIdx.x;

    if (bx == 0) {
        // ---- prep: counting sort by d4 (sh 3) ----
        if (t < 8) u.p.cnt[t] = 0;
        __syncthreads();
        for (int i = t; i < n; i += 256) {
            const int d = digit_of(coords[3*i], coords[3*i+1], coords[3*i+2], 3);
            u.p.digs[i] = (unsigned char)d;
            atomicAdd(&u.p.cnt[d], 1);
        }
        __syncthreads();
        if (t == 0) {
            int run = 0;
            for (int d = 0; d < 8; ++d) {
                u.p.offs[d] = run;
                bases[d] = run;
                run += u.p.cnt[d];
            }
            bases[8] = run;
        }
        __syncthreads();
        for (int i = t; i < n; i += 256) {
            const int pos = atomicAdd(&u.p.offs[u.p.digs[i]], 1);
            perms[pos] = i;
        }
    } else if (bx < 65) {
        // ---- T table: block = (d5, d6), all 8 d7 ----
        const int bb = bx - 1;
        const int d5 = bb >> 3, d6 = bb & 7;
#pragma unroll
        for (int j = 0; j < 2; ++j) {
            const int idx = t + 256*j, d7 = idx >> 6, s = idx & 63;
            float acc = 0.f;
#pragma unroll
            for (int jj = 0; jj < 8; ++jj)
                acc = fmaf(C6[s*64 + d6*8 + jj], C7[jj*8 + d7], acc);
            u.b.S6s[d7][s] = acc;
        }
        __syncthreads();
        float4 creg[16];
#pragma unroll
        for (int s4 = 0; s4 < 16; ++s4)
            creg[s4] = *(const float4*)(C5 + (size_t)t*512 + d5*64 + s4*4);
#pragma unroll 1
        for (int d7 = 0; d7 < 8; ++d7) {
            float acc = 0.f;
#pragma unroll
            for (int s4 = 0; s4 < 16; ++s4) {
                const float4 a = creg[s4];
                const float4 b = *(const float4*)&u.b.S6s[d7][s4*4];
                acc = fmaf(a.x, b.x, acc); acc = fmaf(a.y, b.y, acc);
                acc = fmaf(a.z, b.z, acc); acc = fmaf(a.w, b.w, acc);
            }
            T[(size_t)((d5*8 + d6)*8 + d7)*256 + t] = acc;
        }
    } else {
        // ---- P3 table: block = (d0, d2, d3); rows = 8 d1 values ----
        const int bb = bx - 65;
        const int d3 = bb & 7, d2 = (bb >> 3) & 7, d0 = bb >> 6;
        const float* Cd = C3 + d3 * 256;       // (k,c) at Cd[k*2048 + c]

        // issue async B chunk 0 early
        for (int r = wv; r < 16; r += 4)
            async_load16(Cd + (size_t)r*2048 + ln*4, &u.g.Bs[0][r][ln*4]);

        // v64[d1][c] = sum_r C0[d0,r] * C1[r, d1, c]
#pragma unroll
        for (int j = 0; j < 2; ++j) {
            const int idx = t + 256*j, d1 = idx >> 6, c = idx & 63;
            float acc = 0.f;
#pragma unroll
            for (int r = 0; r < 8; ++r)
                acc = fmaf(C0[d0*8 + r], C1[r*512 + d1*64 + c], acc);
            u.g.v64[d1][c] = acc;
        }
        __syncthreads();

        // As[d1][k] = sum_j v64[d1][j] * C2[j, d2, k]; wave wv owns d1=wv*2+{0,1}
        {
            float4 accA0 = make_float4(0,0,0,0), accA1 = make_float4(0,0,0,0);
#pragma unroll 8
            for (int j = 0; j < 64; ++j) {
                const float4 c2 = *(const float4*)(C2 + (size_t)j*2048 + d2*256 + ln*4);
                fma4(accA0, u.g.v64[wv*2 + 0][j], c2);
                fma4(accA1, u.g.v64[wv*2 + 1][j], c2);
            }
            *(float4*)&u.g.As[wv*2 + 0][ln*4] = accA0;
            *(float4*)&u.g.As[wv*2 + 1][ln*4] = accA1;
        }
        __syncthreads();                        // As + B chunk0 ready

        // main GEMM: K=256 over C3[d3], M=8 (2 rows/wave), N=256
        float4 acc0 = make_float4(0,0,0,0), acc1 = make_float4(0,0,0,0);
        for (int c = 0; c < 16; ++c) {
            if (c + 1 < 16) {
                const int nb = (c+1) & 1;
                for (int r = wv; r < 16; r += 4)
                    async_load16(Cd + (size_t)((c+1)*16 + r)*2048 + ln*4,
                                 &u.g.Bs[nb][r][ln*4]);
            }
            const int cb = c & 1, kb = c * 16;
#pragma unroll 1
            for (int k4 = 0; k4 < 16; k4 += 4) {
                const float4 a0 = *(const float4*)&u.g.As[wv*2 + 0][kb + k4];
                const float4 a1 = *(const float4*)&u.g.As[wv*2 + 1][kb + k4];
                const float4 b0v = *(const float4*)&u.g.Bs[cb][k4+0][ln*4];
                const float4 b1v = *(const float4*)&u.g.Bs[cb][k4+1][ln*4];
                const float4 b2v = *(const float4*)&u.g.Bs[cb][k4+2][ln*4];
                const float4 b3v = *(const float4*)&u.g.Bs[cb][k4+3][ln*4];
                fma4(acc0, a0.x, b0v); fma4(acc0, a0.y, b1v);
                fma4(acc0, a0.z, b2v); fma4(acc0, a0.w, b3v);
                fma4(acc1, a1.x, b0v); fma4(acc1, a1.y, b1v);
                fma4(acc1, a1.z, b2v); fma4(acc1, a1.w, b3v);
            }
            __syncthreads();
        }
        // P3 row index a = d0*512 + d1*64 + d2*8 + d3
        {
            const int a0i = d0*512 + (wv*2 + 0)*64 + d2*8 + d3;
            const int a1i = d0*512 + (wv*2 + 1)*64 + d2*8 + d3;
            *(float4*)(P3 + (size_t)a0i*256 + ln*4) = acc0;
            *(float4*)(P3 + (size_t)a1i*256 + ln*4) = acc1;
        }
    }
}

// ---------------- K2: stage4 (gather P3, x C4[d4]) + fused final -------------
__global__ __launch_bounds__(256, 4) void stage4_final_kernel(
    const float* __restrict__ P3, const float* __restrict__ C4,
    const float* __restrict__ T, const int* __restrict__ coords,
    const int* __restrict__ perm, const int* __restrict__ base,
    float* __restrict__ out)
{
    const int d = blockIdx.x;
    const int b0 = base[d], b1 = base[d + 1];
    const int nrows = b1 - b0;
    const int t = threadIdx.x, ln = t & 63, wv = t >> 6;

    __shared__ __align__(16) float Arm[8][260];
    __shared__ __align__(16) float Bs[2][16][256];
    __shared__ int rows[8], aidx[8], qs[8];

    const float* Cd = C4 + d * 256;

    for (int tile = blockIdx.y; tile * 8 < nrows; tile += (int)gridDim.y) {
        const int row0 = b0 + tile * 8;

        for (int r = wv; r < 16; r += 4)
            async_load16(Cd + (size_t)r*2048 + ln*4, &Bs[0][r][ln*4]);
        if (t < 8) {
            const int gr = row0 + t;
            const int rr = (gr < b1) ? perm[gr] : -1;
            rows[t] = rr;
            int a = 0, q = 0;
            if (rr >= 0) {
                const int x = coords[3*rr], y = coords[3*rr+1], z = coords[3*rr+2];
                a = digit_of(x,y,z,7)*512 + digit_of(x,y,z,6)*64
                  + digit_of(x,y,z,5)*8 + digit_of(x,y,z,4);
                q = digit_of(x,y,z,2)*64 + digit_of(x,y,z,1)*8 + digit_of(x,y,z,0);
            }
            aidx[t] = a; qs[t] = q;
        }
        __syncthreads();

        // gather A (8 x 256) from P3 prefix rows: 512 f4, 2/thread
#pragma unroll
        for (int j = 0; j < 2; ++j) {
            const int idx = t + 256*j, s = idx >> 6, c4 = idx & 63;
            float4 v = make_float4(0,0,0,0);
            if (rows[s] >= 0)
                v = *(const float4*)(P3 + (size_t)aidx[s]*256 + c4*4);
            *(float4*)&Arm[s][c4*4] = v;
        }
        __syncthreads();

        float4 acc0 = make_float4(0,0,0,0), acc1 = make_float4(0,0,0,0);

        for (int c = 0; c < 16; ++c) {
            if (c + 1 < 16) {
                const int nb = (c+1) & 1;
                for (int r = wv; r < 16; r += 4)
                    async_load16(Cd + (size_t)((c+1)*16 + r)*2048 + ln*4,
                                 &Bs[nb][r][ln*4]);
            }
            const int cb = c & 1, kb = c * 16;
#pragma unroll 1
            for (int k4 = 0; k4 < 16; k4 += 4) {
                const float4 a0 = *(const float4*)&Arm[wv*2 + 0][kb + k4];
                const float4 a1 = *(const float4*)&Arm[wv*2 + 1][kb + k4];
                const float4 b0v = *(const float4*)&Bs[cb][k4+0][ln*4];
                const float4 b1v = *(const float4*)&Bs[cb][k4+1][ln*4];
                const float4 b2v = *(const float4*)&Bs[cb][k4+2][ln*4];
                const float4 b3v = *(const float4*)&Bs[cb][k4+3][ln*4];
                fma4(acc0, a0.x, b0v); fma4(acc0, a0.y, b1v);
                fma4(acc0, a0.z, b2v); fma4(acc0, a0.w, b3v);
                fma4(acc1, a1.x, b0v); fma4(acc1, a1.y, b1v);
                fma4(acc1, a1.z, b2v); fma4(acc1, a1.w, b3v);
            }
            __syncthreads();
        }

        // fused final: out[rr] = dot(V4row, T[q]); wave wv owns rows wv*2+{0,1}
#pragma unroll
        for (int i = 0; i < 2; ++i) {
            const int s = wv*2 + i;
            const int rr = rows[s];
            float p = 0.f;
            if (rr >= 0) {
                const float4 a = (i == 0) ? acc0 : acc1;
                const float4 tv = *(const float4*)(T + (size_t)qs[s]*256 + ln*4);
                p = fmaf(a.x, tv.x, fmaf(a.y, tv.y, fmaf(a.z, tv.z, a.w * tv.w)));
            }
            p += __shfl_xor(p, 1);
            p += __shfl_xor(p, 2);
            p += __shfl_xor(p, 4);
            p += __shfl_xor(p, 8);
            p += __shfl_xor(p, 16);
            p += __shfl_xor(p, 32);
            if (ln == 0 && rr >= 0) out[rr] = p;
        }
        __syncthreads();
    }
}

extern "C" void kernel_launch(void* const* d_in, const int* in_sizes, int n_in,
                              void* d_out, int out_size, void* d_ws, size_t ws_size,
                              hipStream_t stream) {
    const float* C0 = (const float*)d_in[0];
    const float* C1 = (const float*)d_in[1];
    const float* C2 = (const float*)d_in[2];
    const float* C3 = (const float*)d_in[3];
    const float* C4 = (const float*)d_in[4];
    const float* C5 = (const float*)d_in[5];
    const float* C6 = (const float*)d_in[6];
    const float* C7 = (const float*)d_in[7];
    const int* coords = (const int*)d_in[8];
    float* out = (float*)d_out;

    const int n = in_sizes[8] / 3;

    // workspace (~4.5 MB)
    float* P3   = (float*)d_ws;                       // 4096*256
    float* Tt   = P3 + 4096*256;                      // 512*256
    int*   perms = (int*)(Tt + 512*256);              // n
    int*   bases = perms + (size_t)n;                 // 9

    tables_kernel<<<577, 256, 0, stream>>>(
        C0, C1, C2, C3, C5, C6, C7, coords, n, perms, bases, P3, Tt);
    stage4_final_kernel<<<dim3(8, 64), 256, 0, stream>>>(
        P3, C4, Tt, coords, perms, bases, out);
}